// Round 7
// baseline (632.288 us; speedup 1.0000x reference)
//
#include <hip/hip_runtime.h>

#define BB 4
#define HH 352
#define WW 1216
#define HW (HH * WW)
#define NPIX (BB * HW)   // 1,712,128
#define TX 4             // pixels per thread in conv kernels (1216 = 4*304)
#define CONV_THREADS 320 // 304 active

// Padded propagation buffer: apron of zeros so bilinear gathers need no
// bounds checks. |rel| <= 4 (encode clamp) => corners in [y-4,y+5]x[x-4,x+5].
#define PAD_T 5
#define PAD_L 8
#define HP (HH + 2 * PAD_T)      // 362
#define WP (WW + 2 * PAD_L)      // 1232
#define HWP (HP * WP)            // 445,984

// SoA tap tables (50 B/px total — prop is table-BW-bound, R6: 27 us/step at
// 68 B/px matched the 81%-of-6.3TB/s model):
//   affp  [9][NPIX] u16 : modulation, fixed point q=round((a+1)*20000).
//                         a_n in [-1,1], a_ref in [0,2] -> q in [0,60000].
//                         Resolution 5e-5 (~2e-4 rel error/step, ~1e-3 over
//                         18 steps — threshold is 2e-2).
//   coordp[8][NPIX] u32 : packed coords, q=round((rel+4)*8192), y lo, x hi.
//                         Resolution 1.2e-4 px (R4-R6: absmax 128 vs 15729).
// Neighbor n -> prop tap k = (n<4 ? n : n+1).
//
// NOTES carried forward:
//  R3: every loop indexing a register array MUST be fully unrolled (runtime
//      index -> scratch demotion, 5.4 GB spill, 8x regression).
//  R5: WRITE_SIZE includes ~160 MB of harness 0xAA-poison writeback draining
//      during our dispatches — don't read it as spill without a FETCH match.
//      A 96-float accumulator exceeds real VGPRs -> AGPR shuffling; hence the
//      two-pass conv split keeping each accumulator <= 64 floats.

// ---------------------------------------------------------------------------
// Kernel A1: offsets pass — 3x3 conv ch 0..15 -> packed coords.
// One image row per block (XCD-swizzled), TX=4 px/thread.
// Channel mapping (verified R2): neighbor n: dy = ch[2n], dx = ch[2n+1].
// ---------------------------------------------------------------------------
__global__ __launch_bounds__(CONV_THREADS) void conv_offsets_kernel(
    const float* __restrict__ guid, const float* __restrict__ w,
    const float* __restrict__ bias, unsigned* __restrict__ coordp)
{
    int tid = threadIdx.x;
    if (tid >= WW / TX) return;            // 304 active
    int bid = blockIdx.x;                  // 0..1407, swizzle: 176 rows/XCD
    int row = (bid & 7) * 176 + (bid >> 3);
    int y = row % HH;
    int b = row / HH;
    int x0 = tid * TX;
    const float* gb = guid + (size_t)b * 8 * HW;

    float acc[16][TX];
#pragma unroll
    for (int o = 0; o < 16; ++o) {
        float bv = bias[o];
#pragma unroll
        for (int tx = 0; tx < TX; ++tx) acc[o][tx] = bv;
    }

#pragma unroll 1
    for (int c = 0; c < 8; ++c) {
        float g[3][6];
#pragma unroll
        for (int r = 0; r < 3; ++r) {
            int yy = y + r - 1;
            bool rv = (yy >= 0) && (yy < HH);   // uniform per block
            const float* gr = gb + (size_t)c * HW + (size_t)yy * WW;
            if (rv) {
                const float4 m = *(const float4*)(gr + x0);
                g[r][1] = m.x; g[r][2] = m.y; g[r][3] = m.z; g[r][4] = m.w;
                g[r][0] = (x0 > 0) ? gr[x0 - 1] : 0.f;
                g[r][5] = (x0 + TX < WW) ? gr[x0 + TX] : 0.f;
            } else {
#pragma unroll
                for (int i = 0; i < 6; ++i) g[r][i] = 0.f;
            }
        }
#pragma unroll
        for (int r = 0; r < 3; ++r) {
#pragma unroll
            for (int i = 0; i < 3; ++i) {
                int tap = r * 3 + i;
#pragma unroll
                for (int o = 0; o < 16; ++o) {
                    float wv = w[o * 72 + c * 9 + tap];  // uniform -> s_load
#pragma unroll
                    for (int tx = 0; tx < TX; ++tx)
                        acc[o][tx] = fmaf(wv, g[r][i + tx], acc[o][tx]);
                }
            }
        }
    }

    int idx0 = row * WW + x0;
#pragma unroll
    for (int n = 0; n < 8; ++n) {
        int k = (n < 4) ? n : n + 1;
        float ky = (float)(k / 3 - 1), kx = (float)(k % 3 - 1);
        unsigned cw[TX];
#pragma unroll
        for (int tx = 0; tx < TX; ++tx) {
            float yr = ky + acc[2 * n][tx];
            float xr = kx + acc[2 * n + 1][tx];
            int yq = (int)lrintf((yr + 4.f) * 8192.f);
            int xq = (int)lrintf((xr + 4.f) * 8192.f);
            yq = min(max(yq, 0), 65535);
            xq = min(max(xq, 0), 65535);
            cw[tx] = (unsigned)yq | ((unsigned)xq << 16);
        }
        uint4 v = make_uint4(cw[0], cw[1], cw[2], cw[3]);
        *(uint4*)(coordp + (size_t)n * NPIX + idx0) = v;
    }
}

// ---------------------------------------------------------------------------
// Kernel A2: affinity pass — 3x3 conv ch 16..23 + TGASS -> u16 aff planes.
// ---------------------------------------------------------------------------
__global__ __launch_bounds__(CONV_THREADS) void conv_aff_kernel(
    const float* __restrict__ guid, const float* __restrict__ w,
    const float* __restrict__ bias, const float* __restrict__ scale_p,
    unsigned short* __restrict__ affp)
{
    int tid = threadIdx.x;
    if (tid >= WW / TX) return;
    int bid = blockIdx.x;
    int row = (bid & 7) * 176 + (bid >> 3);
    int y = row % HH;
    int b = row / HH;
    int x0 = tid * TX;
    const float* gb = guid + (size_t)b * 8 * HW;

    float acc[8][TX];
#pragma unroll
    for (int o = 0; o < 8; ++o) {
        float bv = bias[16 + o];
#pragma unroll
        for (int tx = 0; tx < TX; ++tx) acc[o][tx] = bv;
    }

#pragma unroll 1
    for (int c = 0; c < 8; ++c) {
        float g[3][6];
#pragma unroll
        for (int r = 0; r < 3; ++r) {
            int yy = y + r - 1;
            bool rv = (yy >= 0) && (yy < HH);
            const float* gr = gb + (size_t)c * HW + (size_t)yy * WW;
            if (rv) {
                const float4 m = *(const float4*)(gr + x0);
                g[r][1] = m.x; g[r][2] = m.y; g[r][3] = m.z; g[r][4] = m.w;
                g[r][0] = (x0 > 0) ? gr[x0 - 1] : 0.f;
                g[r][5] = (x0 + TX < WW) ? gr[x0 + TX] : 0.f;
            } else {
#pragma unroll
                for (int i = 0; i < 6; ++i) g[r][i] = 0.f;
            }
        }
#pragma unroll
        for (int r = 0; r < 3; ++r) {
#pragma unroll
            for (int i = 0; i < 3; ++i) {
                int tap = r * 3 + i;
#pragma unroll
                for (int o = 0; o < 8; ++o) {
                    float wv = w[(16 + o) * 72 + c * 9 + tap];
#pragma unroll
                    for (int tx = 0; tx < TX; ++tx)
                        acc[o][tx] = fmaf(wv, g[r][i + tx], acc[o][tx]);
                }
            }
        }
    }

    float sc = scale_p[0] + 1e-8f;
    unsigned short av[9][TX];

#pragma unroll
    for (int tx = 0; tx < TX; ++tx) {
        float a[8];
        float asum = 1e-4f;
#pragma unroll
        for (int n = 0; n < 8; ++n) {
            a[n] = tanhf(acc[n][tx]) / sc;
            asum += fabsf(a[n]);
        }
        asum = fmaxf(asum, 1.0f);
        float ssum = 0.f;
#pragma unroll
        for (int n = 0; n < 8; ++n) { a[n] = a[n] / asum; ssum += a[n]; }
        float aref = 1.0f - ssum;
#pragma unroll
        for (int k = 0; k < 9; ++k) {
            float aval = (k == 4) ? aref : a[(k < 4) ? k : k - 1];
            int q = (int)lrintf((aval + 1.f) * 20000.f);
            q = min(max(q, 0), 65535);
            av[k][tx] = (unsigned short)q;
        }
    }

    int idx0 = row * WW + x0;
#pragma unroll
    for (int k = 0; k < 9; ++k) {
        ushort4 v = make_ushort4(av[k][0], av[k][1], av[k][2], av[k][3]);
        *(ushort4*)(affp + (size_t)k * NPIX + idx0) = v;
    }
}

// ---------------------------------------------------------------------------
// Kernel B: one propagation step, 1 px/thread, padded src, no bounds checks.
// 1D grid XCD-swizzled: xcd = bid&7 owns 11 contiguous 4-row y-bands so its
// featc slice (~1.1 MB over 4 batches) stays L2-resident (R6: featc HBM
// fetch ~8 MB/step vs ~56 unswizzled).
// ---------------------------------------------------------------------------
template <bool MULCONF>
__global__ __launch_bounds__(256) void prop_step_kernel(
    const float* __restrict__ fsrc, const unsigned short* __restrict__ affp,
    const unsigned* __restrict__ coordp, const float* __restrict__ conf,
    float* __restrict__ dst)
{
    int bid = blockIdx.x;                 // 6688 blocks = 8 * 836
    int xcd = bid & 7;
    int s = bid >> 3;                     // 0..835
    int yband = xcd * 11 + s % 11;        // 0..87
    int rest = s / 11;                    // 0..75
    int xb = rest % 19;
    int b = rest / 19;
    int t = threadIdx.x;
    int x = xb * 64 + (t & 63);
    int y = yband * 4 + (t >> 6);
    int idx = (b * HH + y) * WW + x;
    const float* f = fsrc + (size_t)b * HWP;
    int pcenter = (y + PAD_T) * WP + (x + PAD_L);
    float fy = (float)(y + PAD_T - 4);
    float fx = (float)(x + PAD_L - 4);

    // center tap: exact (0,0), one load, no lerp
    float a4 = fmaf((float)affp[(size_t)4 * NPIX + idx], 5e-5f, -1.f);
    float res = a4 * f[pcenter];
#pragma unroll
    for (int n = 0; n < 8; ++n) {
        int k = (n < 4) ? n : n + 1;
        float ak = fmaf((float)affp[(size_t)k * NPIX + idx], 5e-5f, -1.f);
        unsigned cw = coordp[(size_t)n * NPIX + idx];
        float ys = fmaf((float)(cw & 0xffffu), 1.f / 8192.f, fy);
        float xs = fmaf((float)(cw >> 16),     1.f / 8192.f, fx);
        float y0f = floorf(ys), x0f = floorf(xs);
        float wy1 = ys - y0f, wx1 = xs - x0f;
        float wy0 = 1.f - wy1, wx0 = 1.f - wx1;
        int o = (int)y0f * WP + (int)x0f;
        float v00 = f[o], v01 = f[o + 1];
        float v10 = f[o + WP], v11 = f[o + WP + 1];
        float sv = wy0 * (wx0 * v00 + wx1 * v01) + wy1 * (wx0 * v10 + wx1 * v11);
        res = fmaf(ak, sv, res);
    }
    if (MULCONF) {
        res *= conf[idx];
        dst[(size_t)b * HWP + pcenter] = res;
    } else {
        dst[idx] = res;
    }
}

// Zero both padded buffers (apron must be 0; ws is poisoned 0xAA each launch).
__global__ __launch_bounds__(256) void zero_kernel(float4* __restrict__ p, int n4)
{
    int i = blockIdx.x * blockDim.x + threadIdx.x;
    if (i < n4) p[i] = make_float4(0.f, 0.f, 0.f, 0.f);
}

// fc0[padded interior] = feat_init * conf
__global__ __launch_bounds__(256) void mulpad_kernel(
    const float* __restrict__ a, const float* __restrict__ c, float* __restrict__ o)
{
    int t = threadIdx.x;
    int x = blockIdx.x * 64 + (t & 63);
    int y = blockIdx.y * 4 + (t >> 6);
    int b = blockIdx.z;
    int idx = (b * HH + y) * WW + x;
    o[(size_t)b * HWP + (y + PAD_T) * WP + (x + PAD_L)] = a[idx] * c[idx];
}

extern "C" void kernel_launch(void* const* d_in, const int* in_sizes, int n_in,
                              void* d_out, int out_size, void* d_ws, size_t ws_size,
                              hipStream_t stream)
{
    const float* feat_init  = (const float*)d_in[0];
    const float* guidance   = (const float*)d_in[1];
    const float* confidence = (const float*)d_in[2];
    const float* w_oa       = (const float*)d_in[3];
    const float* b_oa       = (const float*)d_in[4];
    const float* aff_scale  = (const float*)d_in[5];
    float* out = (float*)d_out;

    // Workspace: affp u16[9N] | coordp u32[8N] | fc0p f32[BB*HWP] | fc1p
    // (9N*2 bytes = 30,818,304, 16B-aligned since N % 8 == 0)
    const size_t N = (size_t)NPIX;
    unsigned short* affp = (unsigned short*)d_ws;
    unsigned* coordp = (unsigned*)(affp + 9 * N);
    float* fc0 = (float*)(coordp + 8 * N);
    float* fc1 = fc0 + (size_t)BB * HWP;

    const dim3 mgrid(WW / 64, HH / 4, BB);
    const int n4 = 2 * BB * HWP / 4;
    zero_kernel<<<(n4 + 255) / 256, 256, 0, stream>>>((float4*)fc0, n4);
    mulpad_kernel<<<mgrid, 256, 0, stream>>>(feat_init, confidence, fc0);
    conv_offsets_kernel<<<BB * HH, CONV_THREADS, 0, stream>>>(
        guidance, w_oa, b_oa, coordp);
    conv_aff_kernel<<<BB * HH, CONV_THREADS, 0, stream>>>(
        guidance, w_oa, b_oa, aff_scale, affp);

    const int pblocks = (WW / 64) * (HH / 4) * BB;   // 6688
    float* bufs[2] = {fc0, fc1};
    const int T = 18;
    for (int i = 0; i < T; ++i) {
        const float* src = bufs[i & 1];
        if (i < T - 1) {
            float* dst = bufs[(i + 1) & 1];
            prop_step_kernel<true><<<pblocks, 256, 0, stream>>>(
                src, affp, coordp, confidence, dst);
        } else {
            prop_step_kernel<false><<<pblocks, 256, 0, stream>>>(
                src, affp, coordp, confidence, out);
        }
    }
}

// Round 8
// 589.052 us; speedup vs baseline: 1.0734x; 1.0734x over previous
//
#include <hip/hip_runtime.h>

#define BB 4
#define HH 352
#define WW 1216
#define HW (HH * WW)
#define NPIX (BB * HW)   // 1,712,128
#define TX 4             // pixels per thread in conv kernels (1216 = 4*304)
#define CONV_THREADS 320 // 304 active

// Padded propagation buffer: apron of zeros so bilinear gathers need no
// bounds checks. |rel| <= 4 (encode clamp) => corners in [y-4,y+5]x[x-4,x+5].
#define PAD_T 5
#define PAD_L 8
#define HP (HH + 2 * PAD_T)      // 362
#define WP (WW + 2 * PAD_L)      // 1232
#define HWP (HP * WP)            // 445,984

// Prop LDS tile: block covers 64x4 px; samples live in 13 rows x 73 cols;
// stride 76 (banks shift by 12/row; scattered reads ~2 lanes/bank = free).
#define TROWS 13
#define TCOLS 76
#define TSIZE (TROWS * TCOLS)    // 988

// SoA tap tables:
//   affp  [9][NPIX] u16 : modulation, q=round((a+1)*20000), res 5e-5.
//   coordp[8][NPIX] u32 : packed coords, q=round((rel+4)*8192), y lo, x hi.
// Neighbor n -> prop tap k = (n<4 ? n : n+1).
//
// NOTES carried forward:
//  R3: every loop indexing a register array MUST be fully unrolled (runtime
//      index -> scratch demotion, 5.4 GB spill, 8x regression).
//  R5: WRITE_SIZE includes ~160 MB of harness 0xAA-poison writeback; a
//      96-float accumulator -> AGPR shuffling; hence two-pass conv split.
//  R7: prop is NOT HBM-bound at 27 us/step (-26% bytes -> 0 time change);
//      bound is the VMEM gather pipe (~240 cache-line transactions/wave).
//      R4's 2px/thread regression (2x lines/gather -> +27%) corroborates.
//      Hence R8: LDS tile staging, gathers via ds_read2_b32.

// ---------------------------------------------------------------------------
// Kernel A1: offsets pass — 3x3 conv ch 0..15 -> packed coords.
// One image row per block (XCD-swizzled), TX=4 px/thread.
// Channel mapping (verified R2): neighbor n: dy = ch[2n], dx = ch[2n+1].
// ---------------------------------------------------------------------------
__global__ __launch_bounds__(CONV_THREADS) void conv_offsets_kernel(
    const float* __restrict__ guid, const float* __restrict__ w,
    const float* __restrict__ bias, unsigned* __restrict__ coordp)
{
    int tid = threadIdx.x;
    if (tid >= WW / TX) return;            // 304 active
    int bid = blockIdx.x;                  // 0..1407, swizzle: 176 rows/XCD
    int row = (bid & 7) * 176 + (bid >> 3);
    int y = row % HH;
    int b = row / HH;
    int x0 = tid * TX;
    const float* gb = guid + (size_t)b * 8 * HW;

    float acc[16][TX];
#pragma unroll
    for (int o = 0; o < 16; ++o) {
        float bv = bias[o];
#pragma unroll
        for (int tx = 0; tx < TX; ++tx) acc[o][tx] = bv;
    }

#pragma unroll 1
    for (int c = 0; c < 8; ++c) {
        float g[3][6];
#pragma unroll
        for (int r = 0; r < 3; ++r) {
            int yy = y + r - 1;
            bool rv = (yy >= 0) && (yy < HH);   // uniform per block
            const float* gr = gb + (size_t)c * HW + (size_t)yy * WW;
            if (rv) {
                const float4 m = *(const float4*)(gr + x0);
                g[r][1] = m.x; g[r][2] = m.y; g[r][3] = m.z; g[r][4] = m.w;
                g[r][0] = (x0 > 0) ? gr[x0 - 1] : 0.f;
                g[r][5] = (x0 + TX < WW) ? gr[x0 + TX] : 0.f;
            } else {
#pragma unroll
                for (int i = 0; i < 6; ++i) g[r][i] = 0.f;
            }
        }
#pragma unroll
        for (int r = 0; r < 3; ++r) {
#pragma unroll
            for (int i = 0; i < 3; ++i) {
                int tap = r * 3 + i;
#pragma unroll
                for (int o = 0; o < 16; ++o) {
                    float wv = w[o * 72 + c * 9 + tap];  // uniform -> s_load
#pragma unroll
                    for (int tx = 0; tx < TX; ++tx)
                        acc[o][tx] = fmaf(wv, g[r][i + tx], acc[o][tx]);
                }
            }
        }
    }

    int idx0 = row * WW + x0;
#pragma unroll
    for (int n = 0; n < 8; ++n) {
        int k = (n < 4) ? n : n + 1;
        float ky = (float)(k / 3 - 1), kx = (float)(k % 3 - 1);
        unsigned cw[TX];
#pragma unroll
        for (int tx = 0; tx < TX; ++tx) {
            float yr = ky + acc[2 * n][tx];
            float xr = kx + acc[2 * n + 1][tx];
            int yq = (int)lrintf((yr + 4.f) * 8192.f);
            int xq = (int)lrintf((xr + 4.f) * 8192.f);
            yq = min(max(yq, 0), 65535);
            xq = min(max(xq, 0), 65535);
            cw[tx] = (unsigned)yq | ((unsigned)xq << 16);
        }
        uint4 v = make_uint4(cw[0], cw[1], cw[2], cw[3]);
        *(uint4*)(coordp + (size_t)n * NPIX + idx0) = v;
    }
}

// ---------------------------------------------------------------------------
// Kernel A2: affinity pass — 3x3 conv ch 16..23 + TGASS -> u16 aff planes.
// ---------------------------------------------------------------------------
__global__ __launch_bounds__(CONV_THREADS) void conv_aff_kernel(
    const float* __restrict__ guid, const float* __restrict__ w,
    const float* __restrict__ bias, const float* __restrict__ scale_p,
    unsigned short* __restrict__ affp)
{
    int tid = threadIdx.x;
    if (tid >= WW / TX) return;
    int bid = blockIdx.x;
    int row = (bid & 7) * 176 + (bid >> 3);
    int y = row % HH;
    int b = row / HH;
    int x0 = tid * TX;
    const float* gb = guid + (size_t)b * 8 * HW;

    float acc[8][TX];
#pragma unroll
    for (int o = 0; o < 8; ++o) {
        float bv = bias[16 + o];
#pragma unroll
        for (int tx = 0; tx < TX; ++tx) acc[o][tx] = bv;
    }

#pragma unroll 1
    for (int c = 0; c < 8; ++c) {
        float g[3][6];
#pragma unroll
        for (int r = 0; r < 3; ++r) {
            int yy = y + r - 1;
            bool rv = (yy >= 0) && (yy < HH);
            const float* gr = gb + (size_t)c * HW + (size_t)yy * WW;
            if (rv) {
                const float4 m = *(const float4*)(gr + x0);
                g[r][1] = m.x; g[r][2] = m.y; g[r][3] = m.z; g[r][4] = m.w;
                g[r][0] = (x0 > 0) ? gr[x0 - 1] : 0.f;
                g[r][5] = (x0 + TX < WW) ? gr[x0 + TX] : 0.f;
            } else {
#pragma unroll
                for (int i = 0; i < 6; ++i) g[r][i] = 0.f;
            }
        }
#pragma unroll
        for (int r = 0; r < 3; ++r) {
#pragma unroll
            for (int i = 0; i < 3; ++i) {
                int tap = r * 3 + i;
#pragma unroll
                for (int o = 0; o < 8; ++o) {
                    float wv = w[(16 + o) * 72 + c * 9 + tap];
#pragma unroll
                    for (int tx = 0; tx < TX; ++tx)
                        acc[o][tx] = fmaf(wv, g[r][i + tx], acc[o][tx]);
                }
            }
        }
    }

    float sc = scale_p[0] + 1e-8f;
    unsigned short av[9][TX];

#pragma unroll
    for (int tx = 0; tx < TX; ++tx) {
        float a[8];
        float asum = 1e-4f;
#pragma unroll
        for (int n = 0; n < 8; ++n) {
            a[n] = tanhf(acc[n][tx]) / sc;
            asum += fabsf(a[n]);
        }
        asum = fmaxf(asum, 1.0f);
        float ssum = 0.f;
#pragma unroll
        for (int n = 0; n < 8; ++n) { a[n] = a[n] / asum; ssum += a[n]; }
        float aref = 1.0f - ssum;
#pragma unroll
        for (int k = 0; k < 9; ++k) {
            float aval = (k == 4) ? aref : a[(k < 4) ? k : k - 1];
            int q = (int)lrintf((aval + 1.f) * 20000.f);
            q = min(max(q, 0), 65535);
            av[k][tx] = (unsigned short)q;
        }
    }

    int idx0 = row * WW + x0;
#pragma unroll
    for (int k = 0; k < 9; ++k) {
        ushort4 v = make_ushort4(av[k][0], av[k][1], av[k][2], av[k][3]);
        *(ushort4*)(affp + (size_t)k * NPIX + idx0) = v;
    }
}

// ---------------------------------------------------------------------------
// Kernel B: one propagation step. Block = 64x4 px; feat tile (13x76) staged
// in LDS, all bilinear corner reads served by ds_read2_b32 pairs instead of
// divergent global gathers (R7: gather pipe was the bottleneck).
// XCD swizzle: xcd = bid&7 owns 11 contiguous 4-row y-bands -> featc slice
// L2-resident (R6).
// Tile coords: sample row = ly + qy/8192 (the -4 of rel cancels the tile
// origin at y-4); valid range rows [0,12], cols [0,72] within 13x76.
// ---------------------------------------------------------------------------
template <bool MULCONF>
__global__ __launch_bounds__(256) void prop_step_kernel(
    const float* __restrict__ fsrc, const unsigned short* __restrict__ affp,
    const unsigned* __restrict__ coordp, const float* __restrict__ conf,
    float* __restrict__ dst)
{
    __shared__ float tile[TSIZE];

    int bid = blockIdx.x;                 // 6688 blocks = 8 * 836
    int xcd = bid & 7;
    int s = bid >> 3;                     // 0..835
    int yband = xcd * 11 + s % 11;        // 0..87
    int rest = s / 11;                    // 0..75
    int xb = rest % 19;
    int b = rest / 19;
    int t = threadIdx.x;
    int lx = t & 63, ly = t >> 6;
    int x = xb * 64 + lx;
    int y = yband * 4 + ly;
    int idx = (b * HH + y) * WW + x;

    // Hoist independent table loads so they fly across the staging barrier.
    unsigned cw[8];
#pragma unroll
    for (int n = 0; n < 8; ++n) cw[n] = coordp[(size_t)n * NPIX + idx];
    float ak[9];
#pragma unroll
    for (int k = 0; k < 9; ++k)
        ak[k] = fmaf((float)affp[(size_t)k * NPIX + idx], 5e-5f, -1.f);
    float cv = MULCONF ? conf[idx] : 0.f;

    // Stage tile: unpadded rows [y0-4, y0+8], cols [x0-4, x0+71]; all inside
    // the padded buffer (row y0-4 -> padded y0+1 >= 1; col x0-4 -> x0+4).
    {
        const float* gsrc = fsrc + (size_t)b * HWP
                          + (size_t)(yband * 4 + 1) * WP + (xb * 64 + 4);
        for (int i = t; i < TSIZE; i += 256)
            tile[i] = gsrc[(i / TCOLS) * WP + (i % TCOLS)];
    }
    __syncthreads();

    float fy = (float)ly;
    float fx = (float)lx;
    float res = ak[4] * tile[(ly + 4) * TCOLS + (lx + 4)];  // exact center tap
#pragma unroll
    for (int n = 0; n < 8; ++n) {
        float ys = fmaf((float)(cw[n] & 0xffffu), 1.f / 8192.f, fy);
        float xs = fmaf((float)(cw[n] >> 16),     1.f / 8192.f, fx);
        float y0f = floorf(ys), x0f = floorf(xs);
        float wy1 = ys - y0f, wx1 = xs - x0f;
        float wy0 = 1.f - wy1, wx0 = 1.f - wx1;
        int o = (int)y0f * TCOLS + (int)x0f;
        float v00 = tile[o],         v01 = tile[o + 1];          // ds_read2
        float v10 = tile[o + TCOLS], v11 = tile[o + TCOLS + 1];  // ds_read2
        float sv = wy0 * (wx0 * v00 + wx1 * v01) + wy1 * (wx0 * v10 + wx1 * v11);
        int k = (n < 4) ? n : n + 1;
        res = fmaf(ak[k], sv, res);
    }
    if (MULCONF) {
        res *= cv;
        dst[(size_t)b * HWP + (y + PAD_T) * WP + (x + PAD_L)] = res;
    } else {
        dst[idx] = res;
    }
}

// Zero both padded buffers (apron must be 0; ws is poisoned 0xAA each launch).
__global__ __launch_bounds__(256) void zero_kernel(float4* __restrict__ p, int n4)
{
    int i = blockIdx.x * blockDim.x + threadIdx.x;
    if (i < n4) p[i] = make_float4(0.f, 0.f, 0.f, 0.f);
}

// fc0[padded interior] = feat_init * conf
__global__ __launch_bounds__(256) void mulpad_kernel(
    const float* __restrict__ a, const float* __restrict__ c, float* __restrict__ o)
{
    int t = threadIdx.x;
    int x = blockIdx.x * 64 + (t & 63);
    int y = blockIdx.y * 4 + (t >> 6);
    int b = blockIdx.z;
    int idx = (b * HH + y) * WW + x;
    o[(size_t)b * HWP + (y + PAD_T) * WP + (x + PAD_L)] = a[idx] * c[idx];
}

extern "C" void kernel_launch(void* const* d_in, const int* in_sizes, int n_in,
                              void* d_out, int out_size, void* d_ws, size_t ws_size,
                              hipStream_t stream)
{
    const float* feat_init  = (const float*)d_in[0];
    const float* guidance   = (const float*)d_in[1];
    const float* confidence = (const float*)d_in[2];
    const float* w_oa       = (const float*)d_in[3];
    const float* b_oa       = (const float*)d_in[4];
    const float* aff_scale  = (const float*)d_in[5];
    float* out = (float*)d_out;

    // Workspace: affp u16[9N] | coordp u32[8N] | fc0p f32[BB*HWP] | fc1p
    const size_t N = (size_t)NPIX;
    unsigned short* affp = (unsigned short*)d_ws;
    unsigned* coordp = (unsigned*)(affp + 9 * N);
    float* fc0 = (float*)(coordp + 8 * N);
    float* fc1 = fc0 + (size_t)BB * HWP;

    const dim3 mgrid(WW / 64, HH / 4, BB);
    const int n4 = 2 * BB * HWP / 4;
    zero_kernel<<<(n4 + 255) / 256, 256, 0, stream>>>((float4*)fc0, n4);
    mulpad_kernel<<<mgrid, 256, 0, stream>>>(feat_init, confidence, fc0);
    conv_offsets_kernel<<<BB * HH, CONV_THREADS, 0, stream>>>(
        guidance, w_oa, b_oa, coordp);
    conv_aff_kernel<<<BB * HH, CONV_THREADS, 0, stream>>>(
        guidance, w_oa, b_oa, aff_scale, affp);

    const int pblocks = (WW / 64) * (HH / 4) * BB;   // 6688
    float* bufs[2] = {fc0, fc1};
    const int T = 18;
    for (int i = 0; i < T; ++i) {
        const float* src = bufs[i & 1];
        if (i < T - 1) {
            float* dst = bufs[(i + 1) & 1];
            prop_step_kernel<true><<<pblocks, 256, 0, stream>>>(
                src, affp, coordp, confidence, dst);
        } else {
            prop_step_kernel<false><<<pblocks, 256, 0, stream>>>(
                src, affp, coordp, confidence, out);
        }
    }
}